// Round 8
// baseline (213.190 us; speedup 1.0000x reference)
//
#include <hip/hip_runtime.h>
#include <hip/hip_bf16.h>

#define N_NODES 100000
#define N_EDGES 800000
#define HIDDEN 128

typedef short frag_ab __attribute__((ext_vector_type(8)));   // 8 x bf16
typedef float frag_cd __attribute__((ext_vector_type(4)));   // 4 x f32

// round-to-nearest-even fp32 -> bf16 (scalar)
__device__ inline unsigned short f2b(float f) {
    union { float f; unsigned u; } x; x.f = f;
    return (unsigned short)((x.u + 0x7fffu + ((x.u >> 16) & 1u)) >> 16);
}

// packed pair fp32 -> bf16x2 (v_cvt_pk_bf16_f32 on gfx950)
__device__ inline unsigned pk2(float x, float y) {
    union { __hip_bfloat162 h; unsigned u; } c;
    c.h = __float22bfloat162_rn(make_float2(x, y));
    return c.u;
}

// ---------------------------------------------------------------------------
// Kernel 0: transpose+convert W1 (256x128 fp32) -> Bt[256][128] bf16, k-contig.
// ---------------------------------------------------------------------------
__global__ __launch_bounds__(256) void transpose_w1(
    const float* __restrict__ W1, unsigned short* __restrict__ Bt)
{
    const int t  = threadIdx.x;
    const int nc = blockIdx.x * 4 + (t >> 6);
    const int k2 = (t & 63) * 2;
    const int col  = nc & 127;
    const int roff = (nc >= 128) ? 128 : 0;
    float f0 = W1[(size_t)(roff + k2)     * HIDDEN + col];
    float f1 = W1[(size_t)(roff + k2 + 1) * HIDDEN + col];
    *(unsigned*)(Bt + (size_t)nc * HIDDEN + k2) = (unsigned)f2b(f0) | ((unsigned)f2b(f1) << 16);
}

// ---------------------------------------------------------------------------
// Kernel 1 (MFMA GEMM, R8 restructure): BARRIER-FREE, wave-autonomous.
// R5-R7 structure was stuck at ~41 us (vs 16 us stream floor): 4 syncthreads
// per tile, each draining vmcnt(0) — barrier-serialized (m97-class problem).
// Now: each WAVE owns a 16-row panel end-to-end. A loaded straight from
// global into MFMA A-fragments (16 rows x 128 B contiguous per q — coalesced,
// no LDS, no barrier). B streamed from L2-hot Bt inside the nt-loop (4 loads
// + 4 MFMA per nt, ~1:1 VMEM:MFMA, compiler free to pipeline). Epilogue
// transposes through a WAVE-PRIVATE LDS slice (lgkmcnt-ordered within the
// wave, no s_barrier) then stores 512 B-contiguous rows.
// Zero __syncthreads in the entire kernel.
// ---------------------------------------------------------------------------
#define CS_STRIDE 264

__global__ __launch_bounds__(256) void precompute_uv_mfma(
    const float* __restrict__ z, const unsigned short* __restrict__ Bt,
    const float* __restrict__ b1, unsigned short* __restrict__ UV)
{
    __shared__ unsigned short Cs[64 * CS_STRIDE];   // 33.8 KB; wave w owns rows w*16..+15
    const int t = threadIdx.x;
    const int lane = t & 63;
    const int w = t >> 6;
    const int g  = lane >> 4;            // k-octet group 0..3
    const int lc = lane & 15;            // row (A) / col (B) within 16-tile
    const int m0 = blockIdx.x * 64 + w * 16;   // this wave's row panel

    // --- A fragments: direct global fp32 -> packed bf16 (no LDS) ---
    // frag q holds z[m0+lc][q*32 + g*8 .. +7]; per q the wave touches
    // 16 rows x 128 B contiguous — fine coalescing.
    frag_ab a[4];
    {
        int mr = m0 + lc; if (mr > N_NODES - 1) mr = N_NODES - 1;
        const float4* zr = (const float4*)(z + (size_t)mr * HIDDEN);
        #pragma unroll
        for (int q = 0; q < 4; ++q) {
            float4 v0 = zr[q * 8 + g * 2];
            float4 v1 = zr[q * 8 + g * 2 + 1];
            union { frag_ab f; unsigned u[4]; } c;
            c.u[0] = pk2(v0.x, v0.y);
            c.u[1] = pk2(v0.z, v0.w);
            c.u[2] = pk2(v1.x, v1.y);
            c.u[3] = pk2(v1.z, v1.w);
            a[q] = c.f;
        }
    }

    // --- N loop over all 256 output cols: 4 B-loads + 4 MFMA per nt ---
    frag_cd acc[16];
    #pragma unroll
    for (int nt = 0; nt < 16; ++nt)
        acc[nt] = (frag_cd){0.f, 0.f, 0.f, 0.f};

    #pragma unroll
    for (int nt = 0; nt < 16; ++nt) {
        const unsigned short* brow = Bt + (size_t)(nt * 16 + lc) * HIDDEN + g * 8;
        frag_ab b0 = *(const frag_ab*)(brow);
        frag_ab bq1 = *(const frag_ab*)(brow + 32);
        frag_ab bq2 = *(const frag_ab*)(brow + 64);
        frag_ab bq3 = *(const frag_ab*)(brow + 96);
        acc[nt] = __builtin_amdgcn_mfma_f32_16x16x32_bf16(a[0], b0,  acc[nt], 0, 0, 0);
        acc[nt] = __builtin_amdgcn_mfma_f32_16x16x32_bf16(a[1], bq1, acc[nt], 0, 0, 0);
        acc[nt] = __builtin_amdgcn_mfma_f32_16x16x32_bf16(a[2], bq2, acc[nt], 0, 0, 0);
        acc[nt] = __builtin_amdgcn_mfma_f32_16x16x32_bf16(a[3], bq3, acc[nt], 0, 0, 0);
    }

    // --- epilogue: acc -> wave-private LDS slice (C layout: col=lc,
    // row=g*4+r), bias on U half. No barrier: wave-local lgkm ordering. ---
    #pragma unroll
    for (int nt = 0; nt < 16; ++nt) {
        int nc = nt * 16 + lc;
        float bias = (nc < HIDDEN) ? b1[nc] : 0.f;
        #pragma unroll
        for (int r = 0; r < 4; ++r)
            Cs[(w * 16 + g * 4 + r) * CS_STRIDE + nc] = f2b(acc[nt][r] + bias);
    }

    // --- coalesced store: 512 B contiguous per node row ---
    #pragma unroll
    for (int i = 0; i < 8; ++i) {
        int idx = i * 64 + lane;         // 0..511 uint4 slots in the panel
        int row = idx >> 5;              // 0..15
        int c16 = idx & 31;
        int m = m0 + row;
        if (m < N_NODES) {
            uint4 val = *(const uint4*)&Cs[(w * 16 + row) * CS_STRIDE + c16 * 8];
            *(uint4*)&UV[(size_t)m * 256 + c16 * 8] = val;
        }
    }
}

// ---------------------------------------------------------------------------
// Kernel 2: per-edge score = relu(U[src] + V[dst]) . W2 + b2
// UNCHANGED — at the L2-miss-path gather ceiling (~3.5 TB/s, MLP-insensitive).
// ---------------------------------------------------------------------------
__device__ inline float2 bf2(unsigned u) {
    union { unsigned i; float f; } lo, hi;
    lo.i = u << 16;
    hi.i = u & 0xffff0000u;
    return make_float2(lo.f, hi.f);
}

__device__ inline float2 rfma2(unsigned u, unsigned v, float2 w, float2 acc) {
    float2 uf = bf2(u), vf = bf2(v);
    float2 s = make_float2(uf.x + vf.x, uf.y + vf.y);
    s.x = fmaxf(s.x, 0.f); s.y = fmaxf(s.y, 0.f);
    acc.x = __builtin_fmaf(s.x, w.x, acc.x);
    acc.y = __builtin_fmaf(s.y, w.y, acc.y);
    return acc;
}

__global__ __launch_bounds__(256) void edge_score(
    const int* __restrict__ ei, const unsigned short* __restrict__ UV,
    const float* __restrict__ W2, const float* __restrict__ B2,
    float* __restrict__ out)
{
    const int t = threadIdx.x;
    const int g = t & 7;
    const int slot = t >> 3;
    const int e0 = blockIdx.x * 64 + slot;
    const int e1 = e0 + 32;

    const float4* W24 = (const float4*)W2;
    const float4 w0 = W24[g * 4 + 0];
    const float4 w1 = W24[g * 4 + 1];
    const float4 w2 = W24[g * 4 + 2];
    const float4 w3 = W24[g * 4 + 3];

    const int s0 = ei[e0];
    const int d0 = ei[N_EDGES + e0];
    const int s1 = ei[e1];
    const int d1 = ei[N_EDGES + e1];

    const uint4* u0p = (const uint4*)(UV + (size_t)s0 * 256) + g * 2;
    const uint4* v0p = (const uint4*)(UV + (size_t)d0 * 256 + 128) + g * 2;
    const uint4* u1p = (const uint4*)(UV + (size_t)s1 * 256) + g * 2;
    const uint4* v1p = (const uint4*)(UV + (size_t)d1 * 256 + 128) + g * 2;
    const uint4 ua0 = u0p[0], ub0 = u0p[1];
    const uint4 va0 = v0p[0], vb0 = v0p[1];
    const uint4 ua1 = u1p[0], ub1 = u1p[1];
    const uint4 va1 = v1p[0], vb1 = v1p[1];

    float2 A = make_float2(0.f, 0.f), B = make_float2(0.f, 0.f);
    A = rfma2(ua0.x, va0.x, make_float2(w0.x, w0.y), A);
    A = rfma2(ua0.y, va0.y, make_float2(w0.z, w0.w), A);
    A = rfma2(ua0.z, va0.z, make_float2(w1.x, w1.y), A);
    A = rfma2(ua0.w, va0.w, make_float2(w1.z, w1.w), A);
    A = rfma2(ub0.x, vb0.x, make_float2(w2.x, w2.y), A);
    A = rfma2(ub0.y, vb0.y, make_float2(w2.z, w2.w), A);
    A = rfma2(ub0.z, vb0.z, make_float2(w3.x, w3.y), A);
    A = rfma2(ub0.w, vb0.w, make_float2(w3.z, w3.w), A);

    B = rfma2(ua1.x, va1.x, make_float2(w0.x, w0.y), B);
    B = rfma2(ua1.y, va1.y, make_float2(w0.z, w0.w), B);
    B = rfma2(ua1.z, va1.z, make_float2(w1.x, w1.y), B);
    B = rfma2(ua1.w, va1.w, make_float2(w1.z, w1.w), B);
    B = rfma2(ub1.x, vb1.x, make_float2(w2.x, w2.y), B);
    B = rfma2(ub1.y, vb1.y, make_float2(w2.z, w2.w), B);
    B = rfma2(ub1.z, vb1.z, make_float2(w3.x, w3.y), B);
    B = rfma2(ub1.w, vb1.w, make_float2(w3.z, w3.w), B);

    float sa = A.x + A.y;
    float sb = B.x + B.y;
    sa += __shfl_xor(sa, 1, 8);
    sa += __shfl_xor(sa, 2, 8);
    sa += __shfl_xor(sa, 4, 8);
    sb += __shfl_xor(sb, 1, 8);
    sb += __shfl_xor(sb, 2, 8);
    sb += __shfl_xor(sb, 4, 8);

    if (g == 0) {
        float bb = B2[0];
        out[e0] = sa + bb;
        out[e1] = sb + bb;
    }
}

extern "C" void kernel_launch(void* const* d_in, const int* in_sizes, int n_in,
                              void* d_out, int out_size, void* d_ws, size_t ws_size,
                              hipStream_t stream) {
    const float* z  = (const float*)d_in[0];
    const int*   ei = (const int*)d_in[1];
    const float* W1 = (const float*)d_in[2];
    const float* b1 = (const float*)d_in[3];
    const float* W2 = (const float*)d_in[4];
    const float* b2 = (const float*)d_in[5];
    float* out = (float*)d_out;

    unsigned short* UV = (unsigned short*)d_ws;                 // 51.2 MB
    unsigned short* Bt = UV + (size_t)N_NODES * 256;            // 64 KB

    transpose_w1<<<64, 256, 0, stream>>>(W1, Bt);
    precompute_uv_mfma<<<(N_NODES + 63) / 64, 256, 0, stream>>>(z, Bt, b1, UV);
    edge_score<<<N_EDGES / 64, 256, 0, stream>>>(ei, UV, W2, b2, out);
}

// Round 9
// 167.503 us; speedup vs baseline: 1.2727x; 1.2727x over previous
//
#include <hip/hip_runtime.h>
#include <hip/hip_bf16.h>

#define N_NODES 100000
#define N_EDGES 800000
#define HIDDEN 128
#define N_TILES 1563            // ceil(100000 / 64)
#define PC_GRID 768             // 3 blocks/CU residency; ~2 tiles per block

typedef short frag_ab __attribute__((ext_vector_type(8)));   // 8 x bf16
typedef float frag_cd __attribute__((ext_vector_type(4)));   // 4 x f32

// round-to-nearest-even fp32 -> bf16 (scalar)
__device__ inline unsigned short f2b(float f) {
    union { float f; unsigned u; } x; x.f = f;
    return (unsigned short)((x.u + 0x7fffu + ((x.u >> 16) & 1u)) >> 16);
}

// packed pair fp32 -> bf16x2 (v_cvt_pk_bf16_f32 on gfx950)
__device__ inline unsigned pk2(float x, float y) {
    union { __hip_bfloat162 h; unsigned u; } c;
    c.h = __float22bfloat162_rn(make_float2(x, y));
    return c.u;
}

// ---------------------------------------------------------------------------
// Kernel 0: transpose+convert W1 (256x128 fp32) -> Bt[256][128] bf16, k-contig.
// ---------------------------------------------------------------------------
__global__ __launch_bounds__(256) void transpose_w1(
    const float* __restrict__ W1, unsigned short* __restrict__ Bt)
{
    const int t  = threadIdx.x;
    const int nc = blockIdx.x * 4 + (t >> 6);
    const int k2 = (t & 63) * 2;
    const int col  = nc & 127;
    const int roff = (nc >= 128) ? 128 : 0;
    float f0 = W1[(size_t)(roff + k2)     * HIDDEN + col];
    float f1 = W1[(size_t)(roff + k2 + 1) * HIDDEN + col];
    *(unsigned*)(Bt + (size_t)nc * HIDDEN + k2) = (unsigned)f2b(f0) | ((unsigned)f2b(f1) << 16);
}

// ---------------------------------------------------------------------------
// Kernel 1 (MFMA GEMM, persistent): UV = z @ [W1src|W1dst] + [b1|0], bf16 out.
// MEASURED-BEST configuration (R7: 165.6 us wall). Restored after the R8
// barrier-free experiment regressed (79 us: wave-autonomous loads made every
// load instruction a 16-cache-line gather; coalescing >> barrier count here).
// Structure: cooperative lane-contiguous staging (1 KB/instr), cross-tile
// register prefetch, union As/Cs LDS (33.8 KB), packed-cvt bf16, no
// launch_bounds occupancy forcing (R6 proved it causes spill writeback).
// ---------------------------------------------------------------------------
#define AS_STRIDE 136
#define CS_STRIDE 264

__global__ __launch_bounds__(256) void precompute_uv_mfma(
    const float* __restrict__ z, const unsigned short* __restrict__ Bt,
    const float* __restrict__ b1, unsigned short* __restrict__ UV)
{
    __shared__ unsigned short smem[64 * CS_STRIDE];   // 33.8 KB, A and C phases
    const int t = threadIdx.x;
    const int lane = t & 63;
    const int w = t >> 6;
    const int wn = w * 64;
    const int g  = lane >> 4;
    const int lc = lane & 15;

    // --- B fragments + bias: once per block ---
    frag_ab b[4][4];
    float bias[4];
    #pragma unroll
    for (int nt = 0; nt < 4; ++nt) {
        int nc = wn + nt * 16 + lc;
        bias[nt] = (nc < HIDDEN) ? b1[nc] : 0.f;
        const unsigned short* brow = Bt + (size_t)nc * HIDDEN;
        #pragma unroll
        for (int q = 0; q < 4; ++q)
            b[nt][q] = *(const frag_ab*)(brow + q * 32 + g * 8);
    }

    int tile = blockIdx.x;
    uint2 pf[8];   // next A tile, already packed bf16 (16 VGPRs)
    #pragma unroll
    for (int i = 0; i < 8; ++i) {
        int f4 = i * 256 + t;
        int m = tile * 64 + (f4 >> 5);
        if (m >= N_NODES) m = N_NODES - 1;
        float4 v = ((const float4*)z)[(size_t)m * 32 + (f4 & 31)];
        pf[i].x = pk2(v.x, v.y);
        pf[i].y = pk2(v.z, v.w);
    }

    while (true) {
        // --- stage A: packed regs -> LDS ---
        #pragma unroll
        for (int i = 0; i < 8; ++i) {
            int f4 = i * 256 + t;
            *(uint2*)&smem[(f4 >> 5) * AS_STRIDE + (f4 & 31) * 4] = pf[i];
        }
        __syncthreads();

        // --- prefetch NEXT tile (hides HBM latency behind MFMA+epilogue) ---
        const int next = tile + PC_GRID;
        const bool have_next = (next < N_TILES);
        if (have_next) {
            #pragma unroll
            for (int i = 0; i < 8; ++i) {
                int f4 = i * 256 + t;
                int m = next * 64 + (f4 >> 5);
                if (m >= N_NODES) m = N_NODES - 1;
                float4 v = ((const float4*)z)[(size_t)m * 32 + (f4 & 31)];
                pf[i].x = pk2(v.x, v.y);
                pf[i].y = pk2(v.z, v.w);
            }
        }

        // --- K loop: 16 ds_read_b128 + 64 MFMA per wave ---
        frag_cd acc[4][4];
        #pragma unroll
        for (int mt = 0; mt < 4; ++mt)
            #pragma unroll
            for (int nt = 0; nt < 4; ++nt)
                acc[mt][nt] = (frag_cd){0.f, 0.f, 0.f, 0.f};
        #pragma unroll
        for (int q = 0; q < 4; ++q) {
            frag_ab a[4];
            #pragma unroll
            for (int mt = 0; mt < 4; ++mt)
                a[mt] = *(const frag_ab*)&smem[(mt * 16 + lc) * AS_STRIDE + q * 32 + g * 8];
            #pragma unroll
            for (int mt = 0; mt < 4; ++mt)
                #pragma unroll
                for (int nt = 0; nt < 4; ++nt)
                    acc[mt][nt] = __builtin_amdgcn_mfma_f32_16x16x32_bf16(
                        a[mt], b[nt][q], acc[mt][nt], 0, 0, 0);
        }
        __syncthreads();   // A phase over; smem becomes C

        // --- epilogue: acc -> smem (C layout col=lane&15, row=(lane>>4)*4+reg) ---
        #pragma unroll
        for (int nt = 0; nt < 4; ++nt) {
            int nc = wn + nt * 16 + lc;
            #pragma unroll
            for (int mt = 0; mt < 4; ++mt)
                #pragma unroll
                for (int r = 0; r < 4; ++r)
                    smem[(mt * 16 + g * 4 + r) * CS_STRIDE + nc] =
                        f2b(acc[mt][nt][r] + bias[nt]);
        }
        __syncthreads();

        // --- coalesced store: 512 B contiguous per node row ---
        const int m0 = tile * 64;
        #pragma unroll
        for (int i = 0; i < 8; ++i) {
            int f = i * 256 + t;
            int m = f >> 5;
            int c16 = f & 31;
            if (m0 + m < N_NODES) {
                uint4 val = *(const uint4*)&smem[m * CS_STRIDE + c16 * 8];
                *(uint4*)&UV[(size_t)(m0 + m) * 256 + c16 * 8] = val;
            }
        }
        if (!have_next) break;
        __syncthreads();   // C reads done before next stage overwrites
        tile = next;
    }
}

// ---------------------------------------------------------------------------
// Kernel 2: per-edge score = relu(U[src] + V[dst]) . W2 + b2
// UNCHANGED — at the L2-miss-path gather ceiling (~3.5 TB/s; invariant under
// 16->8 lanes/edge, 1->2 edges/thread, 4->8 outstanding loads).
// ---------------------------------------------------------------------------
__device__ inline float2 bf2(unsigned u) {
    union { unsigned i; float f; } lo, hi;
    lo.i = u << 16;
    hi.i = u & 0xffff0000u;
    return make_float2(lo.f, hi.f);
}

__device__ inline float2 rfma2(unsigned u, unsigned v, float2 w, float2 acc) {
    float2 uf = bf2(u), vf = bf2(v);
    float2 s = make_float2(uf.x + vf.x, uf.y + vf.y);
    s.x = fmaxf(s.x, 0.f); s.y = fmaxf(s.y, 0.f);
    acc.x = __builtin_fmaf(s.x, w.x, acc.x);
    acc.y = __builtin_fmaf(s.y, w.y, acc.y);
    return acc;
}

__global__ __launch_bounds__(256) void edge_score(
    const int* __restrict__ ei, const unsigned short* __restrict__ UV,
    const float* __restrict__ W2, const float* __restrict__ B2,
    float* __restrict__ out)
{
    const int t = threadIdx.x;
    const int g = t & 7;
    const int slot = t >> 3;
    const int e0 = blockIdx.x * 64 + slot;
    const int e1 = e0 + 32;

    const float4* W24 = (const float4*)W2;
    const float4 w0 = W24[g * 4 + 0];
    const float4 w1 = W24[g * 4 + 1];
    const float4 w2 = W24[g * 4 + 2];
    const float4 w3 = W24[g * 4 + 3];

    const int s0 = ei[e0];
    const int d0 = ei[N_EDGES + e0];
    const int s1 = ei[e1];
    const int d1 = ei[N_EDGES + e1];

    const uint4* u0p = (const uint4*)(UV + (size_t)s0 * 256) + g * 2;
    const uint4* v0p = (const uint4*)(UV + (size_t)d0 * 256 + 128) + g * 2;
    const uint4* u1p = (const uint4*)(UV + (size_t)s1 * 256) + g * 2;
    const uint4* v1p = (const uint4*)(UV + (size_t)d1 * 256 + 128) + g * 2;
    const uint4 ua0 = u0p[0], ub0 = u0p[1];
    const uint4 va0 = v0p[0], vb0 = v0p[1];
    const uint4 ua1 = u1p[0], ub1 = u1p[1];
    const uint4 va1 = v1p[0], vb1 = v1p[1];

    float2 A = make_float2(0.f, 0.f), B = make_float2(0.f, 0.f);
    A = rfma2(ua0.x, va0.x, make_float2(w0.x, w0.y), A);
    A = rfma2(ua0.y, va0.y, make_float2(w0.z, w0.w), A);
    A = rfma2(ua0.z, va0.z, make_float2(w1.x, w1.y), A);
    A = rfma2(ua0.w, va0.w, make_float2(w1.z, w1.w), A);
    A = rfma2(ub0.x, vb0.x, make_float2(w2.x, w2.y), A);
    A = rfma2(ub0.y, vb0.y, make_float2(w2.z, w2.w), A);
    A = rfma2(ub0.z, vb0.z, make_float2(w3.x, w3.y), A);
    A = rfma2(ub0.w, vb0.w, make_float2(w3.z, w3.w), A);

    B = rfma2(ua1.x, va1.x, make_float2(w0.x, w0.y), B);
    B = rfma2(ua1.y, va1.y, make_float2(w0.z, w0.w), B);
    B = rfma2(ua1.z, va1.z, make_float2(w1.x, w1.y), B);
    B = rfma2(ua1.w, va1.w, make_float2(w1.z, w1.w), B);
    B = rfma2(ub1.x, vb1.x, make_float2(w2.x, w2.y), B);
    B = rfma2(ub1.y, vb1.y, make_float2(w2.z, w2.w), B);
    B = rfma2(ub1.z, vb1.z, make_float2(w3.x, w3.y), B);
    B = rfma2(ub1.w, vb1.w, make_float2(w3.z, w3.w), B);

    float sa = A.x + A.y;
    float sb = B.x + B.y;
    sa += __shfl_xor(sa, 1, 8);
    sa += __shfl_xor(sa, 2, 8);
    sa += __shfl_xor(sa, 4, 8);
    sb += __shfl_xor(sb, 1, 8);
    sb += __shfl_xor(sb, 2, 8);
    sb += __shfl_xor(sb, 4, 8);

    if (g == 0) {
        float bb = B2[0];
        out[e0] = sa + bb;
        out[e1] = sb + bb;
    }
}

extern "C" void kernel_launch(void* const* d_in, const int* in_sizes, int n_in,
                              void* d_out, int out_size, void* d_ws, size_t ws_size,
                              hipStream_t stream) {
    const float* z  = (const float*)d_in[0];
    const int*   ei = (const int*)d_in[1];
    const float* W1 = (const float*)d_in[2];
    const float* b1 = (const float*)d_in[3];
    const float* W2 = (const float*)d_in[4];
    const float* b2 = (const float*)d_in[5];
    float* out = (float*)d_out;

    unsigned short* UV = (unsigned short*)d_ws;                 // 51.2 MB
    unsigned short* Bt = UV + (size_t)N_NODES * 256;            // 64 KB

    transpose_w1<<<64, 256, 0, stream>>>(W1, Bt);
    precompute_uv_mfma<<<PC_GRID, 256, 0, stream>>>(z, Bt, b1, UV);
    edge_score<<<N_EDGES / 64, 256, 0, stream>>>(ei, UV, W2, b2, out);
}

// Round 10
// 162.049 us; speedup vs baseline: 1.3156x; 1.0337x over previous
//
#include <hip/hip_runtime.h>
#include <hip/hip_bf16.h>

#define N_NODES 100000
#define N_EDGES 800000
#define HIDDEN 128
#define N_TILES 1563            // ceil(100000 / 64)
#define PC_GRID 512             // 2 blocks/CU residency (VGPR >128 => 8 waves/CU);
                                // ~3 tiles/block so prefetch covers 2 of 3 A-loads
                                // and there is NO ragged second dispatch pass
                                // (R9's 768 assumed 3/CU and serialized 256 blocks).

typedef short frag_ab __attribute__((ext_vector_type(8)));   // 8 x bf16
typedef float frag_cd __attribute__((ext_vector_type(4)));   // 4 x f32

// round-to-nearest-even fp32 -> bf16 (scalar)
__device__ inline unsigned short f2b(float f) {
    union { float f; unsigned u; } x; x.f = f;
    return (unsigned short)((x.u + 0x7fffu + ((x.u >> 16) & 1u)) >> 16);
}

// packed pair fp32 -> bf16x2 (v_cvt_pk_bf16_f32 on gfx950)
__device__ inline unsigned pk2(float x, float y) {
    union { __hip_bfloat162 h; unsigned u; } c;
    c.h = __float22bfloat162_rn(make_float2(x, y));
    return c.u;
}

// ---------------------------------------------------------------------------
// Kernel 0: transpose+convert W1 (256x128 fp32) -> Bt[256][128] bf16, k-contig.
// ---------------------------------------------------------------------------
__global__ __launch_bounds__(256) void transpose_w1(
    const float* __restrict__ W1, unsigned short* __restrict__ Bt)
{
    const int t  = threadIdx.x;
    const int nc = blockIdx.x * 4 + (t >> 6);
    const int k2 = (t & 63) * 2;
    const int col  = nc & 127;
    const int roff = (nc >= 128) ? 128 : 0;
    float f0 = W1[(size_t)(roff + k2)     * HIDDEN + col];
    float f1 = W1[(size_t)(roff + k2 + 1) * HIDDEN + col];
    *(unsigned*)(Bt + (size_t)nc * HIDDEN + k2) = (unsigned)f2b(f0) | ((unsigned)f2b(f1) << 16);
}

// ---------------------------------------------------------------------------
// Kernel 1 (MFMA GEMM, persistent): UV = z @ [W1src|W1dst] + [b1|0], bf16 out.
// Measured-best structure (R7/R9: ~165.6-167.5 us wall). Cooperative
// lane-contiguous staging (1 KB/instr), cross-tile register prefetch,
// union As/Cs LDS (33.8 KB), packed-cvt bf16, no launch_bounds forcing
// (R6: forcing -> VGPR 84 -> 60 MB spill writeback). R8 proved barrier-free
// wave-autonomous loads regress 2x (address divergence >> barrier drain).
// R10 change: PC_GRID 768 -> 512 only.
// ---------------------------------------------------------------------------
#define AS_STRIDE 136
#define CS_STRIDE 264

__global__ __launch_bounds__(256) void precompute_uv_mfma(
    const float* __restrict__ z, const unsigned short* __restrict__ Bt,
    const float* __restrict__ b1, unsigned short* __restrict__ UV)
{
    __shared__ unsigned short smem[64 * CS_STRIDE];   // 33.8 KB, A and C phases
    const int t = threadIdx.x;
    const int lane = t & 63;
    const int w = t >> 6;
    const int wn = w * 64;
    const int g  = lane >> 4;
    const int lc = lane & 15;

    // --- B fragments + bias: once per block ---
    frag_ab b[4][4];
    float bias[4];
    #pragma unroll
    for (int nt = 0; nt < 4; ++nt) {
        int nc = wn + nt * 16 + lc;
        bias[nt] = (nc < HIDDEN) ? b1[nc] : 0.f;
        const unsigned short* brow = Bt + (size_t)nc * HIDDEN;
        #pragma unroll
        for (int q = 0; q < 4; ++q)
            b[nt][q] = *(const frag_ab*)(brow + q * 32 + g * 8);
    }

    int tile = blockIdx.x;
    uint2 pf[8];   // next A tile, already packed bf16 (16 VGPRs)
    #pragma unroll
    for (int i = 0; i < 8; ++i) {
        int f4 = i * 256 + t;
        int m = tile * 64 + (f4 >> 5);
        if (m >= N_NODES) m = N_NODES - 1;
        float4 v = ((const float4*)z)[(size_t)m * 32 + (f4 & 31)];
        pf[i].x = pk2(v.x, v.y);
        pf[i].y = pk2(v.z, v.w);
    }

    while (true) {
        // --- stage A: packed regs -> LDS ---
        #pragma unroll
        for (int i = 0; i < 8; ++i) {
            int f4 = i * 256 + t;
            *(uint2*)&smem[(f4 >> 5) * AS_STRIDE + (f4 & 31) * 4] = pf[i];
        }
        __syncthreads();

        // --- prefetch NEXT tile (hides HBM latency behind MFMA+epilogue) ---
        const int next = tile + PC_GRID;
        const bool have_next = (next < N_TILES);
        if (have_next) {
            #pragma unroll
            for (int i = 0; i < 8; ++i) {
                int f4 = i * 256 + t;
                int m = next * 64 + (f4 >> 5);
                if (m >= N_NODES) m = N_NODES - 1;
                float4 v = ((const float4*)z)[(size_t)m * 32 + (f4 & 31)];
                pf[i].x = pk2(v.x, v.y);
                pf[i].y = pk2(v.z, v.w);
            }
        }

        // --- K loop: 16 ds_read_b128 + 64 MFMA per wave ---
        frag_cd acc[4][4];
        #pragma unroll
        for (int mt = 0; mt < 4; ++mt)
            #pragma unroll
            for (int nt = 0; nt < 4; ++nt)
                acc[mt][nt] = (frag_cd){0.f, 0.f, 0.f, 0.f};
        #pragma unroll
        for (int q = 0; q < 4; ++q) {
            frag_ab a[4];
            #pragma unroll
            for (int mt = 0; mt < 4; ++mt)
                a[mt] = *(const frag_ab*)&smem[(mt * 16 + lc) * AS_STRIDE + q * 32 + g * 8];
            #pragma unroll
            for (int mt = 0; mt < 4; ++mt)
                #pragma unroll
                for (int nt = 0; nt < 4; ++nt)
                    acc[mt][nt] = __builtin_amdgcn_mfma_f32_16x16x32_bf16(
                        a[mt], b[nt][q], acc[mt][nt], 0, 0, 0);
        }
        __syncthreads();   // A phase over; smem becomes C

        // --- epilogue: acc -> smem (C layout col=lane&15, row=(lane>>4)*4+reg) ---
        #pragma unroll
        for (int nt = 0; nt < 4; ++nt) {
            int nc = wn + nt * 16 + lc;
            #pragma unroll
            for (int mt = 0; mt < 4; ++mt)
                #pragma unroll
                for (int r = 0; r < 4; ++r)
                    smem[(mt * 16 + g * 4 + r) * CS_STRIDE + nc] =
                        f2b(acc[mt][nt][r] + bias[nt]);
        }
        __syncthreads();

        // --- coalesced store: 512 B contiguous per node row ---
        const int m0 = tile * 64;
        #pragma unroll
        for (int i = 0; i < 8; ++i) {
            int f = i * 256 + t;
            int m = f >> 5;
            int c16 = f & 31;
            if (m0 + m < N_NODES) {
                uint4 val = *(const uint4*)&smem[m * CS_STRIDE + c16 * 8];
                *(uint4*)&UV[(size_t)(m0 + m) * 256 + c16 * 8] = val;
            }
        }
        if (!have_next) break;
        __syncthreads();   // C reads done before next stage overwrites
        tile = next;
    }
}

// ---------------------------------------------------------------------------
// Kernel 2: per-edge score = relu(U[src] + V[dst]) . W2 + b2
// UNCHANGED — at the L2-miss-path gather ceiling (~3.5 TB/s; invariant under
// 16->8 lanes/edge, 1->2 edges/thread, 4->8 outstanding loads).
// ---------------------------------------------------------------------------
__device__ inline float2 bf2(unsigned u) {
    union { unsigned i; float f; } lo, hi;
    lo.i = u << 16;
    hi.i = u & 0xffff0000u;
    return make_float2(lo.f, hi.f);
}

__device__ inline float2 rfma2(unsigned u, unsigned v, float2 w, float2 acc) {
    float2 uf = bf2(u), vf = bf2(v);
    float2 s = make_float2(uf.x + vf.x, uf.y + vf.y);
    s.x = fmaxf(s.x, 0.f); s.y = fmaxf(s.y, 0.f);
    acc.x = __builtin_fmaf(s.x, w.x, acc.x);
    acc.y = __builtin_fmaf(s.y, w.y, acc.y);
    return acc;
}

__global__ __launch_bounds__(256) void edge_score(
    const int* __restrict__ ei, const unsigned short* __restrict__ UV,
    const float* __restrict__ W2, const float* __restrict__ B2,
    float* __restrict__ out)
{
    const int t = threadIdx.x;
    const int g = t & 7;
    const int slot = t >> 3;
    const int e0 = blockIdx.x * 64 + slot;
    const int e1 = e0 + 32;

    const float4* W24 = (const float4*)W2;
    const float4 w0 = W24[g * 4 + 0];
    const float4 w1 = W24[g * 4 + 1];
    const float4 w2 = W24[g * 4 + 2];
    const float4 w3 = W24[g * 4 + 3];

    const int s0 = ei[e0];
    const int d0 = ei[N_EDGES + e0];
    const int s1 = ei[e1];
    const int d1 = ei[N_EDGES + e1];

    const uint4* u0p = (const uint4*)(UV + (size_t)s0 * 256) + g * 2;
    const uint4* v0p = (const uint4*)(UV + (size_t)d0 * 256 + 128) + g * 2;
    const uint4* u1p = (const uint4*)(UV + (size_t)s1 * 256) + g * 2;
    const uint4* v1p = (const uint4*)(UV + (size_t)d1 * 256 + 128) + g * 2;
    const uint4 ua0 = u0p[0], ub0 = u0p[1];
    const uint4 va0 = v0p[0], vb0 = v0p[1];
    const uint4 ua1 = u1p[0], ub1 = u1p[1];
    const uint4 va1 = v1p[0], vb1 = v1p[1];

    float2 A = make_float2(0.f, 0.f), B = make_float2(0.f, 0.f);
    A = rfma2(ua0.x, va0.x, make_float2(w0.x, w0.y), A);
    A = rfma2(ua0.y, va0.y, make_float2(w0.z, w0.w), A);
    A = rfma2(ua0.z, va0.z, make_float2(w1.x, w1.y), A);
    A = rfma2(ua0.w, va0.w, make_float2(w1.z, w1.w), A);
    A = rfma2(ub0.x, vb0.x, make_float2(w2.x, w2.y), A);
    A = rfma2(ub0.y, vb0.y, make_float2(w2.z, w2.w), A);
    A = rfma2(ub0.z, vb0.z, make_float2(w3.x, w3.y), A);
    A = rfma2(ub0.w, vb0.w, make_float2(w3.z, w3.w), A);

    B = rfma2(ua1.x, va1.x, make_float2(w0.x, w0.y), B);
    B = rfma2(ua1.y, va1.y, make_float2(w0.z, w0.w), B);
    B = rfma2(ua1.z, va1.z, make_float2(w1.x, w1.y), B);
    B = rfma2(ua1.w, va1.w, make_float2(w1.z, w1.w), B);
    B = rfma2(ub1.x, vb1.x, make_float2(w2.x, w2.y), B);
    B = rfma2(ub1.y, vb1.y, make_float2(w2.z, w2.w), B);
    B = rfma2(ub1.z, vb1.z, make_float2(w3.x, w3.y), B);
    B = rfma2(ub1.w, vb1.w, make_float2(w3.z, w3.w), B);

    float sa = A.x + A.y;
    float sb = B.x + B.y;
    sa += __shfl_xor(sa, 1, 8);
    sa += __shfl_xor(sa, 2, 8);
    sa += __shfl_xor(sa, 4, 8);
    sb += __shfl_xor(sb, 1, 8);
    sb += __shfl_xor(sb, 2, 8);
    sb += __shfl_xor(sb, 4, 8);

    if (g == 0) {
        float bb = B2[0];
        out[e0] = sa + bb;
        out[e1] = sb + bb;
    }
}

extern "C" void kernel_launch(void* const* d_in, const int* in_sizes, int n_in,
                              void* d_out, int out_size, void* d_ws, size_t ws_size,
                              hipStream_t stream) {
    const float* z  = (const float*)d_in[0];
    const int*   ei = (const int*)d_in[1];
    const float* W1 = (const float*)d_in[2];
    const float* b1 = (const float*)d_in[3];
    const float* W2 = (const float*)d_in[4];
    const float* b2 = (const float*)d_in[5];
    float* out = (float*)d_out;

    unsigned short* UV = (unsigned short*)d_ws;                 // 51.2 MB
    unsigned short* Bt = UV + (size_t)N_NODES * 256;            // 64 KB

    transpose_w1<<<64, 256, 0, stream>>>(W1, Bt);
    precompute_uv_mfma<<<PC_GRID, 256, 0, stream>>>(z, Bt, b1, UV);
    edge_score<<<N_EDGES / 64, 256, 0, stream>>>(ei, UV, W2, b2, out);
}